// Round 13
// baseline (237.412 us; speedup 1.0000x reference)
//
#include <hip/hip_runtime.h>
#include <math.h>

#define LRELU_SLOPE 0.2f
#define NEG_INF __int_as_float(0xff800000)

typedef float f32x4 __attribute__((ext_vector_type(4)));
typedef _Float16 f16x8 __attribute__((ext_vector_type(8)));
typedef _Float16 f16x2 __attribute__((ext_vector_type(2)));
typedef unsigned short us8 __attribute__((ext_vector_type(8)));

__device__ __forceinline__ void atomicMaxF(float* addr, float v) {
  if (v >= 0.f) atomicMax((int*)addr, __float_as_int(v));
  else atomicMin((unsigned int*)addr, (unsigned int)__float_as_int(v));
}

__device__ __forceinline__ unsigned short f2h(float f) {
  _Float16 h = (_Float16)f;                       // v_cvt_f16_f32 (RNE)
  return __builtin_bit_cast(unsigned short, h);
}
__device__ __forceinline__ float2 up2(unsigned int u) {
  f16x2 h = __builtin_bit_cast(f16x2, u);
  return make_float2((float)h.x, (float)h.y);
}

// acc += (f32)(f16 half of g) * w   -- one VOP3P v_fma_mix_f32, no cvt
__device__ __forceinline__ void fmix_lo(float& acc, unsigned int g, float w) {
  asm("v_fma_mix_f32 %0, %1, %2, %0 op_sel_hi:[1,0,0]"
      : "+v"(acc) : "v"(g), "v"(w));
}
__device__ __forceinline__ void fmix_hi(float& acc, unsigned int g, float w) {
  asm("v_fma_mix_f32 %0, %1, %2, %0 op_sel:[1,0,0] op_sel_hi:[1,0,0]"
      : "+v"(acc) : "v"(g), "v"(w));
}
__device__ __forceinline__ void fmix8(float* a, uint4 g, float w) {
  fmix_lo(a[0], g.x, w); fmix_hi(a[1], g.x, w);
  fmix_lo(a[2], g.y, w); fmix_hi(a[3], g.y, w);
  fmix_lo(a[4], g.z, w); fmix_hi(a[5], g.z, w);
  fmix_lo(a[6], g.w, w); fmix_hi(a[7], g.w, w);
}

// async global->LDS, 16B per lane; LDS dest must be the wave-uniform base
__device__ __forceinline__ void async_copy16(const unsigned short* g, unsigned short* l) {
  __builtin_amdgcn_global_load_lds(
      (const __attribute__((address_space(1))) void*)g,
      (__attribute__((address_space(3))) void*)l, 16, 0, 0);
}

// ---------------- W pre-pass: transpose + cvt to fp16 --------------------------
__global__ void conv_w(const float* __restrict__ W1, const float* __restrict__ W2,
                       unsigned short* __restrict__ t1, unsigned short* __restrict__ t2) {
  const float* W = blockIdx.y ? W2 : W1;
  unsigned short* t = blockIdx.y ? t2 : t1;
  int k = blockIdx.x, n = threadIdx.x;
  t[n * 256 + k] = f2h(W[k * 256 + n]);
}

// ---------------- X pre-pass: f32 -> fp16 --------------------------------------
__global__ __launch_bounds__(256) void conv_x(
    const float* __restrict__ x, unsigned short* __restrict__ xo, int total) {
  int base = (blockIdx.x * 256 + threadIdx.x) * 4;
  if (base >= total) return;
  float4 v = *(const float4*)(x + base);
  ushort4 h;
  h.x = f2h(v.x); h.y = f2h(v.y); h.z = f2h(v.z); h.w = f2h(v.w);
  *(ushort4*)(xo + base) = h;
}

// ---------------- GEMM + fused attention coefficients --------------------------
// Cfp16[M,256] = A[M,256] @ B^T (fp16 MFMA, f32 accum).
// Each wave's 64 output cols = one full head -> a_s/a_d computed exactly from
// f32 acc via 4 FMAs/row + 16-lane shfl reduce, written once (no atomics).
__global__ __launch_bounds__(256) void gemm_mfma(
    const unsigned short* __restrict__ A, const unsigned short* __restrict__ Bt,
    const float* __restrict__ att_s, const float* __restrict__ att_d,
    unsigned short* __restrict__ C, float* __restrict__ a_s,
    float* __restrict__ a_d, int M) {
  __shared__ __align__(16) unsigned short sA[128 * 64];
  __shared__ __align__(16) unsigned short sB[128 * 64];
  const int tid = threadIdx.x;
  const int lane = tid & 63;
  const int wave = tid >> 6;
  const int wr = wave >> 1, wc = wave & 1;
  const int bm = blockIdx.x * 128;
  const int bn = blockIdx.y * 128;

  const int srow = lane >> 3;                          // 0..7
  const int scol = (((lane & 7) ^ (lane >> 3)) << 3);  // swizzled ushort col

  f32x4 acc[4][4];
#pragma unroll
  for (int i = 0; i < 4; ++i)
#pragma unroll
    for (int j = 0; j < 4; ++j) acc[i][j] = (f32x4){0.f, 0.f, 0.f, 0.f};

  for (int kc = 0; kc < 256; kc += 64) {
#pragma unroll
    for (int i = 0; i < 4; ++i) {
      const int r0 = wave * 32 + i * 8;
      const size_t ga = (size_t)(bm + r0 + srow) * 256 + kc + scol;
      const size_t gb = (size_t)(bn + r0 + srow) * 256 + kc + scol;
      async_copy16(A + ga, &sA[r0 * 64]);
      async_copy16(Bt + gb, &sB[r0 * 64]);
    }
    __syncthreads();
#pragma unroll
    for (int ks = 0; ks < 64; ks += 32) {
      const int kbase = ks + ((lane >> 4) << 3);
      const int kx = kbase ^ ((lane & 7) << 3);
      f16x8 af[4], bf[4];
#pragma unroll
      for (int f = 0; f < 4; ++f) {
        int ar = wr * 64 + f * 16 + (lane & 15);
        int br = wc * 64 + f * 16 + (lane & 15);
        af[f] = __builtin_bit_cast(f16x8, *(const us8*)&sA[ar * 64 + kx]);
        bf[f] = __builtin_bit_cast(f16x8, *(const us8*)&sB[br * 64 + kx]);
      }
#pragma unroll
      for (int i = 0; i < 4; ++i)
#pragma unroll
        for (int j = 0; j < 4; ++j)
          acc[i][j] = __builtin_amdgcn_mfma_f32_16x16x32_f16(af[i], bf[j], acc[i][j], 0, 0, 0);
    }
    __syncthreads();
  }

  // ---- fused attention coefficients: head = blockIdx.y*2 + wc
  const int head = blockIdx.y * 2 + wc;
  float ws[4], wd[4];
#pragma unroll
  for (int j = 0; j < 4; ++j) {
    ws[j] = att_s[head * 64 + j * 16 + (lane & 15)];
    wd[j] = att_d[head * 64 + j * 16 + (lane & 15)];
  }
#pragma unroll
  for (int i = 0; i < 4; ++i) {
#pragma unroll
    for (int r = 0; r < 4; ++r) {
      float ps = 0.f, pd = 0.f;
#pragma unroll
      for (int j = 0; j < 4; ++j) {
        ps = fmaf(acc[i][j][r], ws[j], ps);
        pd = fmaf(acc[i][j][r], wd[j], pd);
      }
#pragma unroll
      for (int off = 1; off < 16; off <<= 1) {
        ps += __shfl_xor(ps, off);
        pd += __shfl_xor(pd, off);
      }
      int row = bm + wr * 64 + i * 16 + ((lane >> 4) << 2) + r;
      if ((lane & 15) == 0 && row < M) {
        a_s[row * 4 + head] = ps;
        a_d[row * 4 + head] = pd;
      }
    }
  }

  // ---- C store (fp16). m=(lane>>4)*4+reg, n=lane&15 within each 16x16 frag
#pragma unroll
  for (int i = 0; i < 4; ++i) {
#pragma unroll
    for (int r = 0; r < 4; ++r) {
      int row = bm + wr * 64 + i * 16 + ((lane >> 4) << 2) + r;
      if (row < M) {
#pragma unroll
        for (int j = 0; j < 4; ++j)
          C[(size_t)row * 256 + bn + wc * 64 + j * 16 + (lane & 15)] = f2h(acc[i][j][r]);
      }
    }
  }
}

// ---------------- misc init ---------------------------------------------------
__global__ void init_misc(int* __restrict__ count, float* __restrict__ pooled,
                          int N_, int G_) {
  int t = blockIdx.x * 256 + threadIdx.x;
  if (t < N_) count[t] = 1;                 // self loop
  if (t < G_ * 256) pooled[t] = NEG_INF;
}

// ---------------- CSR build ----------------------------------------------------
__global__ void hist_k(const int* __restrict__ dst, int* __restrict__ count, int E_) {
  int t = blockIdx.x * 256 + threadIdx.x;
  if (t < E_) atomicAdd(&count[dst[t]], 1);
}

#define SCB 1024

__global__ __launch_bounds__(256) void scan_phaseA(
    const int* __restrict__ count, int* __restrict__ bsum, int N_) {
  int t = threadIdx.x;
  int base = blockIdx.x * SCB + t * 4;
  int s = 0;
  if (base + 3 < N_) {
    int4 v = *(const int4*)(count + base);
    s = v.x + v.y + v.z + v.w;
  } else {
#pragma unroll
    for (int k = 0; k < 4; ++k) if (base + k < N_) s += count[base + k];
  }
#pragma unroll
  for (int off = 32; off > 0; off >>= 1) s += __shfl_xor(s, off);
  __shared__ int red[4];
  int wave = t >> 6, lane = t & 63;
  if (lane == 0) red[wave] = s;
  __syncthreads();
  if (t == 0) bsum[blockIdx.x] = red[0] + red[1] + red[2] + red[3];
}

__global__ __launch_bounds__(256) void scan_phaseB(
    const int* __restrict__ bsum, int* __restrict__ boff, int nb) {
  __shared__ int tmp[256];
  int t = threadIdx.x;
  int v = (t < nb) ? bsum[t] : 0;
  tmp[t] = v;
  __syncthreads();
  for (int off = 1; off < 256; off <<= 1) {
    int u = (t >= off) ? tmp[t - off] : 0;
    __syncthreads();
    tmp[t] += u;
    __syncthreads();
  }
  if (t < nb) boff[t] = tmp[t] - v;  // exclusive
  if (t == 0) boff[nb] = tmp[255];   // grand total
}

__global__ __launch_bounds__(256) void scan_phaseC(
    const int* __restrict__ count, const int* __restrict__ boff,
    int* __restrict__ rowptr, int* __restrict__ nxt, int N_, int nb) {
  __shared__ int tmp[256];
  int t = threadIdx.x;
  int base = blockIdx.x * SCB + t * 4;
  int4 v = make_int4(0, 0, 0, 0);
  if (base + 3 < N_) {
    v = *(const int4*)(count + base);
  } else {
    if (base + 0 < N_) v.x = count[base + 0];
    if (base + 1 < N_) v.y = count[base + 1];
    if (base + 2 < N_) v.z = count[base + 2];
  }
  int s = v.x + v.y + v.z + v.w;
  tmp[t] = s;
  __syncthreads();
  for (int off = 1; off < 256; off <<= 1) {
    int u = (t >= off) ? tmp[t - off] : 0;
    __syncthreads();
    tmp[t] += u;
    __syncthreads();
  }
  int run = boff[blockIdx.x] + tmp[t] - s;
  int4 rp;
  rp.x = run; run += v.x;
  rp.y = run; run += v.y;
  rp.z = run; run += v.z;
  rp.w = run;
  if (base + 3 < N_) {
    *(int4*)(rowptr + base) = rp;
    *(int4*)(nxt + base) = rp;
  } else {
    if (base + 0 < N_) { rowptr[base + 0] = rp.x; nxt[base + 0] = rp.x; }
    if (base + 1 < N_) { rowptr[base + 1] = rp.y; nxt[base + 1] = rp.y; }
    if (base + 2 < N_) { rowptr[base + 2] = rp.z; nxt[base + 2] = rp.z; }
  }
  if (blockIdx.x == 0 && t == 0) rowptr[N_] = boff[nb];
}

__global__ void scatter_k(const int* __restrict__ src, const int* __restrict__ dst,
                          int* __restrict__ nxt, int* __restrict__ colx,
                          int* __restrict__ rowx, int E_, int N_) {
  int t = blockIdx.x * 256 + threadIdx.x;
  if (t >= E_ + N_) return;
  int s = (t < E_) ? src[t] : (t - E_);
  int d = (t < E_) ? dst[t] : (t - E_);
  int pos = atomicAdd(&nxt[d], 1);
  colx[pos] = s;
  rowx[pos] = d;
}

// ---------------- per-slot softmax weights, head-major: ewt[head][slot] --------
__global__ __launch_bounds__(256) void edge_w(
    const int* __restrict__ colx, const int* __restrict__ rowx,
    const float* __restrict__ a_s, const float* __restrict__ a_d,
    float* __restrict__ ewt, int T) {
  int t = blockIdx.x * 256 + threadIdx.x;
  if (t >= T) return;
  int s = colx[t], d = rowx[t];
  float4 as4 = *(const float4*)(a_s + (size_t)s * 4);
  float4 ad4 = *(const float4*)(a_d + (size_t)d * 4);
  float l;
  l = as4.x + ad4.x; l = l > 0.f ? l : LRELU_SLOPE * l; ewt[0 * (size_t)T + t] = __expf(l);
  l = as4.y + ad4.y; l = l > 0.f ? l : LRELU_SLOPE * l; ewt[1 * (size_t)T + t] = __expf(l);
  l = as4.z + ad4.z; l = l > 0.f ? l : LRELU_SLOPE * l; ewt[2 * (size_t)T + t] = __expf(l);
  l = as4.w + ad4.w; l = l > 0.f ? l : LRELU_SLOPE * l; ewt[3 * (size_t)T + t] = __expf(l);
}

// ---------------- aggregation: 2 edges/wave-instr, v_fma_mix accumulate -------
__global__ __launch_bounds__(256) void agg(
    const unsigned short* __restrict__ h, const int* __restrict__ rowptr,
    const int* __restrict__ colx, const float* __restrict__ ewt, int T,
    const float* __restrict__ bias, unsigned short* __restrict__ out, int N_) {
  const int wave = threadIdx.x >> 6;
  const int lane = threadIdx.x & 63;
  const int n = blockIdx.x * 4 + wave;
  if (n >= N_) return;
  const int half = lane >> 5;          // which edge of the pair
  const int lc = lane & 31;            // 32 lanes cover 256 channels
  const int head = lc >> 3;            // 8 lanes per head
  const float* ewh = ewt + (size_t)head * T;
  const size_t choff = (size_t)lc * 8; // ushort offset (16B per lane)
  const int e0 = rowptr[n], e1 = rowptr[n + 1];
  float a[8] = {0.f, 0.f, 0.f, 0.f, 0.f, 0.f, 0.f, 0.f};
  float dsum = 0.f;
  int j = e0;
  // 4 edges per iteration: two pair-steps, independent gathers in flight
  for (; j + 4 <= e1; j += 4) {
    int s0 = colx[j + half];
    int s1 = colx[j + 2 + half];
    float w0 = ewh[j + half];
    float w1 = ewh[j + 2 + half];
    uint4 g0 = *(const uint4*)(h + (size_t)s0 * 256 + choff);
    uint4 g1 = *(const uint4*)(h + (size_t)s1 * 256 + choff);
    dsum += w0 + w1;
    fmix8(a, g0, w0);
    fmix8(a, g1, w1);
  }
  // 2-edge step
  for (; j + 2 <= e1; j += 2) {
    int s0 = colx[j + half];
    float w0 = ewh[j + half];
    uint4 g0 = *(const uint4*)(h + (size_t)s0 * 256 + choff);
    dsum += w0;
    fmix8(a, g0, w0);
  }
  // last single edge: upper half contributes zero (w masked)
  if (j < e1) {
    int s0 = colx[j];
    float w0 = half ? 0.f : ewh[j];
    uint4 g0 = *(const uint4*)(h + (size_t)s0 * 256 + choff);
    dsum += w0;
    fmix8(a, g0, w0);
  }
  // combine the two half-waves (lane l <-> l+32, same channels/head)
#pragma unroll
  for (int u = 0; u < 8; ++u) a[u] += __shfl_xor(a[u], 32);
  dsum += __shfl_xor(dsum, 32);
  if (half == 0) {
    const float inv = 1.f / (dsum + 1e-16f);
    const float4 bA = *(const float4*)(bias + lc * 8);
    const float4 bB = *(const float4*)(bias + lc * 8 + 4);
    float v;
    us8 o;
    v = a[0] * inv + bA.x; o[0] = f2h(v > 0.f ? v : expm1f(v));
    v = a[1] * inv + bA.y; o[1] = f2h(v > 0.f ? v : expm1f(v));
    v = a[2] * inv + bA.z; o[2] = f2h(v > 0.f ? v : expm1f(v));
    v = a[3] * inv + bA.w; o[3] = f2h(v > 0.f ? v : expm1f(v));
    v = a[4] * inv + bB.x; o[4] = f2h(v > 0.f ? v : expm1f(v));
    v = a[5] * inv + bB.y; o[5] = f2h(v > 0.f ? v : expm1f(v));
    v = a[6] * inv + bB.z; o[6] = f2h(v > 0.f ? v : expm1f(v));
    v = a[7] * inv + bB.w; o[7] = f2h(v > 0.f ? v : expm1f(v));
    *(us8*)(out + (size_t)n * 256 + choff) = o;
  }
}

// ---------------- graph max-pool from fp16 (batch is sorted) -------------------
#define PNB 32
__global__ __launch_bounds__(256) void pool_max(
    const unsigned short* __restrict__ fb, const int* __restrict__ batch,
    float* __restrict__ pooled, int N_) {
  const int c2 = threadIdx.x & 127;        // channels 2*c2, 2*c2+1
  const int slot = threadIdx.x >> 7;       // 2 slots x 16 nodes
  const int ns = blockIdx.x * PNB + slot * 16;
  const int ne = min(ns + 16, N_);
  if (ns >= N_) return;
  float r0 = NEG_INF, r1 = NEG_INF;
  int g = batch[ns];
#pragma unroll 4
  for (int n = ns; n < ne; ++n) {
    int gn = batch[n];
    unsigned int w = *(const unsigned int*)(fb + (size_t)n * 256 + c2 * 2);
    if (gn != g) {
      atomicMaxF(&pooled[(size_t)g * 256 + c2 * 2], r0);
      atomicMaxF(&pooled[(size_t)g * 256 + c2 * 2 + 1], r1);
      r0 = r1 = NEG_INF; g = gn;
    }
    float2 xv = up2(w);
    r0 = fmaxf(r0, xv.x);
    r1 = fmaxf(r1, xv.y);
  }
  atomicMaxF(&pooled[(size_t)g * 256 + c2 * 2], r0);
  atomicMaxF(&pooled[(size_t)g * 256 + c2 * 2 + 1], r1);
}

// ---------------- head: fixup -inf, lin1 (256->128), lin2 (128->2) ------------
__global__ __launch_bounds__(128) void head_k(
    const float* __restrict__ pooled, const float* __restrict__ w1,
    const float* __restrict__ b1, const float* __restrict__ w2,
    const float* __restrict__ b2, float* __restrict__ out) {
  __shared__ float ps[256];
  __shared__ float z1[128];
  int g = blockIdx.x;
  int t = threadIdx.x;
  for (int i = t; i < 256; i += 128) {
    float v = pooled[(size_t)g * 256 + i];
    if (v < -1e37f) v = 0.f;   // empty-graph guard (isneginf -> 0)
    ps[i] = v;
  }
  __syncthreads();
  float a = b1[t];
  for (int k = 0; k < 256; ++k) a = fmaf(ps[k], w1[k * 128 + t], a);
  z1[t] = a;
  __syncthreads();
  if (t < 2) {
    float a2 = b2[t];
    for (int j = 0; j < 128; ++j) a2 = fmaf(z1[j], w2[j * 2 + t], a2);
    out[g * 2 + t] = a2;
  }
}

// ---------------- driver --------------------------------------------------------
extern "C" void kernel_launch(void* const* d_in, const int* in_sizes, int n_in,
                              void* d_out, int out_size, void* d_ws, size_t ws_size,
                              hipStream_t stream) {
  const int N = in_sizes[2];         // batch array length = #nodes
  const int E = in_sizes[1] / 2;     // edge_index is [2,E]
  const int G = out_size / 2;        // output [G,2]
  const int T = E + N;               // CSR slots (incl. self loops)
  const int Tpad = ((T + 3) / 4) * 4;
  const int Npad = ((N + 127) / 128) * 128;

  const float* x     = (const float*)d_in[0];
  const int*   ei    = (const int*)d_in[1];
  const int*   src   = ei;
  const int*   dst   = ei + E;
  const int*   batch = (const int*)d_in[2];
  const float* W1    = (const float*)d_in[3];
  const float* atts1 = (const float*)d_in[4];
  const float* attd1 = (const float*)d_in[5];
  const float* b1    = (const float*)d_in[6];
  const float* W2    = (const float*)d_in[7];
  const float* atts2 = (const float*)d_in[8];
  const float* attd2 = (const float*)d_in[9];
  const float* b2    = (const float*)d_in[10];
  const float* l1w   = (const float*)d_in[11];
  const float* l1b   = (const float*)d_in[12];
  const float* l2w   = (const float*)d_in[13];
  const float* l2b   = (const float*)d_in[14];

  uintptr_t p = (uintptr_t)d_ws;
  auto alloc = [&](size_t bytes) -> void* {
    p = (p + 255) & ~(uintptr_t)255;
    void* r = (void*)p;
    p += bytes;
    return r;
  };
  const int nb = (N + SCB - 1) / SCB;
  unsigned short* hbuf = (unsigned short*)alloc((size_t)N * 256 * 2);     // fp16 h (GEMM out)
  unsigned short* xbuf = (unsigned short*)alloc((size_t)Npad * 256 * 2);  // fp16 x
  unsigned short* fbuf = (unsigned short*)alloc((size_t)Npad * 256 * 2);  // fp16 agg out
  float* a_s    = (float*)alloc((size_t)N * 4 * 4);
  float* a_d    = (float*)alloc((size_t)N * 4 * 4);
  float* pooled = (float*)alloc((size_t)G * 256 * 4);
  int*   count  = (int*)alloc((size_t)N * 4);
  int*   rowptr = (int*)alloc((size_t)(N + 1) * 4);
  int*   nxt    = (int*)alloc((size_t)N * 4);
  int*   colx   = (int*)alloc((size_t)Tpad * 4);
  int*   rowx   = (int*)alloc((size_t)Tpad * 4);
  float* ewt    = (float*)alloc((size_t)Tpad * 4 * 4);
  int*   bsum   = (int*)alloc((size_t)nb * 4);
  int*   boff   = (int*)alloc((size_t)(nb + 1) * 4);
  unsigned short* wt1 = (unsigned short*)alloc(256 * 256 * 2);
  unsigned short* wt2 = (unsigned short*)alloc(256 * 256 * 2);

  dim3 blk(256);
  dim3 gemmGrid(Npad / 128, 2);
  int initRange = max(N, G * 256);
  int xtot = N * 256;

  // pre-passes + CSR build (shared by both layers) + init
  conv_w<<<dim3(256, 2), blk, 0, stream>>>(W1, W2, wt1, wt2);
  conv_x<<<(xtot / 4 + 255) / 256, blk, 0, stream>>>(x, xbuf, xtot);
  init_misc<<<(initRange + 255) / 256, blk, 0, stream>>>(count, pooled, N, G);
  hist_k<<<(E + 255) / 256, blk, 0, stream>>>(dst, count, E);
  scan_phaseA<<<nb, blk, 0, stream>>>(count, bsum, N);
  scan_phaseB<<<1, blk, 0, stream>>>(bsum, boff, nb);
  scan_phaseC<<<nb, blk, 0, stream>>>(count, boff, rowptr, nxt, N, nb);
  scatter_k<<<(T + 255) / 256, blk, 0, stream>>>(src, dst, nxt, colx, rowx, E, N);

  // ---- layer 1
  gemm_mfma<<<gemmGrid, blk, 0, stream>>>(xbuf, wt1, atts1, attd1, hbuf, a_s, a_d, N);
  edge_w<<<(T + 255) / 256, blk, 0, stream>>>(colx, rowx, a_s, a_d, ewt, Tpad);
  agg<<<(N + 3) / 4, blk, 0, stream>>>(hbuf, rowptr, colx, ewt, Tpad, b1, fbuf, N);

  // ---- layer 2
  gemm_mfma<<<gemmGrid, blk, 0, stream>>>(fbuf, wt2, atts2, attd2, hbuf, a_s, a_d, N);
  edge_w<<<(T + 255) / 256, blk, 0, stream>>>(colx, rowx, a_s, a_d, ewt, Tpad);
  agg<<<(N + 3) / 4, blk, 0, stream>>>(hbuf, rowptr, colx, ewt, Tpad, b2, fbuf, N);

  // ---- pool + head
  pool_max<<<(N + PNB - 1) / PNB, blk, 0, stream>>>(fbuf, batch, pooled, N);
  head_k<<<G, 128, 0, stream>>>(pooled, l1w, l1b, l2w, l2b, (float*)d_out);
}

// Round 14
// 230.403 us; speedup vs baseline: 1.0304x; 1.0304x over previous
//
#include <hip/hip_runtime.h>
#include <math.h>

#define LRELU_SLOPE 0.2f
#define NEG_INF __int_as_float(0xff800000)

typedef float f32x4 __attribute__((ext_vector_type(4)));
typedef _Float16 f16x8 __attribute__((ext_vector_type(8)));
typedef _Float16 f16x2 __attribute__((ext_vector_type(2)));
typedef unsigned short us8 __attribute__((ext_vector_type(8)));

__device__ __forceinline__ void atomicMaxF(float* addr, float v) {
  if (v >= 0.f) atomicMax((int*)addr, __float_as_int(v));
  else atomicMin((unsigned int*)addr, (unsigned int)__float_as_int(v));
}

__device__ __forceinline__ unsigned short f2h(float f) {
  _Float16 h = (_Float16)f;                       // v_cvt_f16_f32 (RNE)
  return __builtin_bit_cast(unsigned short, h);
}
__device__ __forceinline__ float2 up2(unsigned int u) {
  f16x2 h = __builtin_bit_cast(f16x2, u);
  return make_float2((float)h.x, (float)h.y);
}

// async global->LDS, 16B per lane; LDS dest must be the wave-uniform base
__device__ __forceinline__ void async_copy16(const unsigned short* g, unsigned short* l) {
  __builtin_amdgcn_global_load_lds(
      (const __attribute__((address_space(1))) void*)g,
      (__attribute__((address_space(3))) void*)l, 16, 0, 0);
}

// ---------------- fused pre-pass: W transpose+cvt (blocks 0..511), x cvt ------
__global__ __launch_bounds__(256) void conv_wx(
    const float* __restrict__ W1, const float* __restrict__ W2,
    unsigned short* __restrict__ t1, unsigned short* __restrict__ t2,
    const float* __restrict__ x, unsigned short* __restrict__ xo, int total) {
  int b = blockIdx.x;
  if (b < 512) {                      // W pre-pass: transpose + cvt to fp16
    const float* W = (b >= 256) ? W2 : W1;
    unsigned short* t = (b >= 256) ? t2 : t1;
    int k = b & 255, n = threadIdx.x;
    t[n * 256 + k] = f2h(W[k * 256 + n]);
    return;
  }
  int base = ((b - 512) * 256 + threadIdx.x) * 4;
  if (base >= total) return;
  float4 v = *(const float4*)(x + base);
  ushort4 h;
  h.x = f2h(v.x); h.y = f2h(v.y); h.z = f2h(v.z); h.w = f2h(v.w);
  *(ushort4*)(xo + base) = h;
}

// ---------------- GEMM + fused attention coefficients --------------------------
// Cfp16[M,256] = A[M,256] @ B^T (fp16 MFMA, f32 accum).
// Each wave's 64 output cols = one full head -> a_s/a_d computed exactly from
// f32 acc via 4 FMAs/row + 16-lane shfl reduce, written once (no atomics).
__global__ __launch_bounds__(256) void gemm_mfma(
    const unsigned short* __restrict__ A, const unsigned short* __restrict__ Bt,
    const float* __restrict__ att_s, const float* __restrict__ att_d,
    unsigned short* __restrict__ C, float* __restrict__ a_s,
    float* __restrict__ a_d, int M) {
  __shared__ __align__(16) unsigned short sA[128 * 64];
  __shared__ __align__(16) unsigned short sB[128 * 64];
  const int tid = threadIdx.x;
  const int lane = tid & 63;
  const int wave = tid >> 6;
  const int wr = wave >> 1, wc = wave & 1;
  const int bm = blockIdx.x * 128;
  const int bn = blockIdx.y * 128;

  const int srow = lane >> 3;                          // 0..7
  const int scol = (((lane & 7) ^ (lane >> 3)) << 3);  // swizzled ushort col

  f32x4 acc[4][4];
#pragma unroll
  for (int i = 0; i < 4; ++i)
#pragma unroll
    for (int j = 0; j < 4; ++j) acc[i][j] = (f32x4){0.f, 0.f, 0.f, 0.f};

  for (int kc = 0; kc < 256; kc += 64) {
#pragma unroll
    for (int i = 0; i < 4; ++i) {
      const int r0 = wave * 32 + i * 8;
      const size_t ga = (size_t)(bm + r0 + srow) * 256 + kc + scol;
      const size_t gb = (size_t)(bn + r0 + srow) * 256 + kc + scol;
      async_copy16(A + ga, &sA[r0 * 64]);
      async_copy16(Bt + gb, &sB[r0 * 64]);
    }
    __syncthreads();
#pragma unroll
    for (int ks = 0; ks < 64; ks += 32) {
      const int kbase = ks + ((lane >> 4) << 3);
      const int kx = kbase ^ ((lane & 7) << 3);
      f16x8 af[4], bf[4];
#pragma unroll
      for (int f = 0; f < 4; ++f) {
        int ar = wr * 64 + f * 16 + (lane & 15);
        int br = wc * 64 + f * 16 + (lane & 15);
        af[f] = __builtin_bit_cast(f16x8, *(const us8*)&sA[ar * 64 + kx]);
        bf[f] = __builtin_bit_cast(f16x8, *(const us8*)&sB[br * 64 + kx]);
      }
#pragma unroll
      for (int i = 0; i < 4; ++i)
#pragma unroll
        for (int j = 0; j < 4; ++j)
          acc[i][j] = __builtin_amdgcn_mfma_f32_16x16x32_f16(af[i], bf[j], acc[i][j], 0, 0, 0);
    }
    __syncthreads();
  }

  // ---- fused attention coefficients: head = blockIdx.y*2 + wc
  const int head = blockIdx.y * 2 + wc;
  float ws[4], wd[4];
#pragma unroll
  for (int j = 0; j < 4; ++j) {
    ws[j] = att_s[head * 64 + j * 16 + (lane & 15)];
    wd[j] = att_d[head * 64 + j * 16 + (lane & 15)];
  }
#pragma unroll
  for (int i = 0; i < 4; ++i) {
#pragma unroll
    for (int r = 0; r < 4; ++r) {
      float ps = 0.f, pd = 0.f;
#pragma unroll
      for (int j = 0; j < 4; ++j) {
        ps = fmaf(acc[i][j][r], ws[j], ps);
        pd = fmaf(acc[i][j][r], wd[j], pd);
      }
#pragma unroll
      for (int off = 1; off < 16; off <<= 1) {
        ps += __shfl_xor(ps, off);
        pd += __shfl_xor(pd, off);
      }
      int row = bm + wr * 64 + i * 16 + ((lane >> 4) << 2) + r;
      if ((lane & 15) == 0 && row < M) {
        a_s[row * 4 + head] = ps;
        a_d[row * 4 + head] = pd;
      }
    }
  }

  // ---- C store (fp16). m=(lane>>4)*4+reg, n=lane&15 within each 16x16 frag
#pragma unroll
  for (int i = 0; i < 4; ++i) {
#pragma unroll
    for (int r = 0; r < 4; ++r) {
      int row = bm + wr * 64 + i * 16 + ((lane >> 4) << 2) + r;
      if (row < M) {
#pragma unroll
        for (int j = 0; j < 4; ++j)
          C[(size_t)row * 256 + bn + wc * 64 + j * 16 + (lane & 15)] = f2h(acc[i][j][r]);
      }
    }
  }
}

// ---------------- misc init ---------------------------------------------------
__global__ void init_misc(int* __restrict__ count, float* __restrict__ pooled,
                          int N_, int G_) {
  int t = blockIdx.x * 256 + threadIdx.x;
  if (t < N_) count[t] = 1;                 // self loop
  if (t < G_ * 256) pooled[t] = NEG_INF;
}

// ---------------- CSR build ----------------------------------------------------
__global__ void hist_k(const int* __restrict__ dst, int* __restrict__ count, int E_) {
  int t = blockIdx.x * 256 + threadIdx.x;
  if (t < E_) atomicAdd(&count[dst[t]], 1);
}

#define SCB 1024

__global__ __launch_bounds__(256) void scan_phaseA(
    const int* __restrict__ count, int* __restrict__ bsum, int N_) {
  int t = threadIdx.x;
  int base = blockIdx.x * SCB + t * 4;
  int s = 0;
  if (base + 3 < N_) {
    int4 v = *(const int4*)(count + base);
    s = v.x + v.y + v.z + v.w;
  } else {
#pragma unroll
    for (int k = 0; k < 4; ++k) if (base + k < N_) s += count[base + k];
  }
#pragma unroll
  for (int off = 32; off > 0; off >>= 1) s += __shfl_xor(s, off);
  __shared__ int red[4];
  int wave = t >> 6, lane = t & 63;
  if (lane == 0) red[wave] = s;
  __syncthreads();
  if (t == 0) bsum[blockIdx.x] = red[0] + red[1] + red[2] + red[3];
}

__global__ __launch_bounds__(256) void scan_phaseB(
    const int* __restrict__ bsum, int* __restrict__ boff, int nb) {
  __shared__ int tmp[256];
  int t = threadIdx.x;
  int v = (t < nb) ? bsum[t] : 0;
  tmp[t] = v;
  __syncthreads();
  for (int off = 1; off < 256; off <<= 1) {
    int u = (t >= off) ? tmp[t - off] : 0;
    __syncthreads();
    tmp[t] += u;
    __syncthreads();
  }
  if (t < nb) boff[t] = tmp[t] - v;  // exclusive
  if (t == 0) boff[nb] = tmp[255];   // grand total
}

__global__ __launch_bounds__(256) void scan_phaseC(
    const int* __restrict__ count, const int* __restrict__ boff,
    int* __restrict__ rowptr, int* __restrict__ nxt, int N_, int nb) {
  __shared__ int tmp[256];
  int t = threadIdx.x;
  int base = blockIdx.x * SCB + t * 4;
  int4 v = make_int4(0, 0, 0, 0);
  if (base + 3 < N_) {
    v = *(const int4*)(count + base);
  } else {
    if (base + 0 < N_) v.x = count[base + 0];
    if (base + 1 < N_) v.y = count[base + 1];
    if (base + 2 < N_) v.z = count[base + 2];
  }
  int s = v.x + v.y + v.z + v.w;
  tmp[t] = s;
  __syncthreads();
  for (int off = 1; off < 256; off <<= 1) {
    int u = (t >= off) ? tmp[t - off] : 0;
    __syncthreads();
    tmp[t] += u;
    __syncthreads();
  }
  int run = boff[blockIdx.x] + tmp[t] - s;
  int4 rp;
  rp.x = run; run += v.x;
  rp.y = run; run += v.y;
  rp.z = run; run += v.z;
  rp.w = run;
  if (base + 3 < N_) {
    *(int4*)(rowptr + base) = rp;
    *(int4*)(nxt + base) = rp;
  } else {
    if (base + 0 < N_) { rowptr[base + 0] = rp.x; nxt[base + 0] = rp.x; }
    if (base + 1 < N_) { rowptr[base + 1] = rp.y; nxt[base + 1] = rp.y; }
    if (base + 2 < N_) { rowptr[base + 2] = rp.z; nxt[base + 2] = rp.z; }
  }
  if (blockIdx.x == 0 && t == 0) rowptr[N_] = boff[nb];
}

__global__ void scatter_k(const int* __restrict__ src, const int* __restrict__ dst,
                          int* __restrict__ nxt, int* __restrict__ colx,
                          int* __restrict__ rowx, int E_, int N_) {
  int t = blockIdx.x * 256 + threadIdx.x;
  if (t >= E_ + N_) return;
  int s = (t < E_) ? src[t] : (t - E_);
  int d = (t < E_) ? dst[t] : (t - E_);
  int pos = atomicAdd(&nxt[d], 1);
  colx[pos] = s;
  rowx[pos] = d;
}

// ---------------- per-slot softmax weights, head-major: ewt[head][slot] --------
__global__ __launch_bounds__(256) void edge_w(
    const int* __restrict__ colx, const int* __restrict__ rowx,
    const float* __restrict__ a_s, const float* __restrict__ a_d,
    float* __restrict__ ewt, int T) {
  int t = blockIdx.x * 256 + threadIdx.x;
  if (t >= T) return;
  int s = colx[t], d = rowx[t];
  float4 as4 = *(const float4*)(a_s + (size_t)s * 4);
  float4 ad4 = *(const float4*)(a_d + (size_t)d * 4);
  float l;
  l = as4.x + ad4.x; l = l > 0.f ? l : LRELU_SLOPE * l; ewt[0 * (size_t)T + t] = __expf(l);
  l = as4.y + ad4.y; l = l > 0.f ? l : LRELU_SLOPE * l; ewt[1 * (size_t)T + t] = __expf(l);
  l = as4.z + ad4.z; l = l > 0.f ? l : LRELU_SLOPE * l; ewt[2 * (size_t)T + t] = __expf(l);
  l = as4.w + ad4.w; l = l > 0.f ? l : LRELU_SLOPE * l; ewt[3 * (size_t)T + t] = __expf(l);
}

// ---------------- aggregation: 2 edges per wave-instruction -------------------
// lane owns 8 channels (16B); half-waves process different edges concurrently.
// out[n,c] = elu( (sum_e w_e * h[s_e,c]) / sum_e w_e + bias[c] )
__global__ __launch_bounds__(256) void agg(
    const unsigned short* __restrict__ h, const int* __restrict__ rowptr,
    const int* __restrict__ colx, const float* __restrict__ ewt, int T,
    const float* __restrict__ bias, unsigned short* __restrict__ out, int N_) {
  const int wave = threadIdx.x >> 6;
  const int lane = threadIdx.x & 63;
  const int n = blockIdx.x * 4 + wave;
  if (n >= N_) return;
  const int half = lane >> 5;          // which edge of the pair
  const int lc = lane & 31;            // 32 lanes cover 256 channels
  const int head = lc >> 3;            // 8 lanes per head
  const float* ewh = ewt + (size_t)head * T;
  const size_t choff = (size_t)lc * 8; // ushort offset (16B per lane)
  const int e0 = rowptr[n], e1 = rowptr[n + 1];
  f32x4 accA = (f32x4){0.f, 0.f, 0.f, 0.f};
  f32x4 accB = (f32x4){0.f, 0.f, 0.f, 0.f};
  float dsum = 0.f;
  int j = e0;
  // 4 edges per iteration: two pair-steps, independent gathers in flight
  for (; j + 4 <= e1; j += 4) {
    int s0 = colx[j + half];
    int s1 = colx[j + 2 + half];
    float w0 = ewh[j + half];
    float w1 = ewh[j + 2 + half];
    uint4 g0 = *(const uint4*)(h + (size_t)s0 * 256 + choff);
    uint4 g1 = *(const uint4*)(h + (size_t)s1 * 256 + choff);
    dsum += w0 + w1;
    float2 p0 = up2(g0.x), p1 = up2(g0.y), p2 = up2(g0.z), p3 = up2(g0.w);
    accA.x = fmaf(w0, p0.x, accA.x); accA.y = fmaf(w0, p0.y, accA.y);
    accA.z = fmaf(w0, p1.x, accA.z); accA.w = fmaf(w0, p1.y, accA.w);
    accB.x = fmaf(w0, p2.x, accB.x); accB.y = fmaf(w0, p2.y, accB.y);
    accB.z = fmaf(w0, p3.x, accB.z); accB.w = fmaf(w0, p3.y, accB.w);
    float2 q0 = up2(g1.x), q1 = up2(g1.y), q2 = up2(g1.z), q3 = up2(g1.w);
    accA.x = fmaf(w1, q0.x, accA.x); accA.y = fmaf(w1, q0.y, accA.y);
    accA.z = fmaf(w1, q1.x, accA.z); accA.w = fmaf(w1, q1.y, accA.w);
    accB.x = fmaf(w1, q2.x, accB.x); accB.y = fmaf(w1, q2.y, accB.y);
    accB.z = fmaf(w1, q3.x, accB.z); accB.w = fmaf(w1, q3.y, accB.w);
  }
  // 2-edge step
  for (; j + 2 <= e1; j += 2) {
    int s0 = colx[j + half];
    float w0 = ewh[j + half];
    uint4 g0 = *(const uint4*)(h + (size_t)s0 * 256 + choff);
    dsum += w0;
    float2 p0 = up2(g0.x), p1 = up2(g0.y), p2 = up2(g0.z), p3 = up2(g0.w);
    accA.x = fmaf(w0, p0.x, accA.x); accA.y = fmaf(w0, p0.y, accA.y);
    accA.z = fmaf(w0, p1.x, accA.z); accA.w = fmaf(w0, p1.y, accA.w);
    accB.x = fmaf(w0, p2.x, accB.x); accB.y = fmaf(w0, p2.y, accB.y);
    accB.z = fmaf(w0, p3.x, accB.z); accB.w = fmaf(w0, p3.y, accB.w);
  }
  // last single edge: upper half contributes zero (w masked)
  if (j < e1) {
    int s0 = colx[j];
    float w0 = half ? 0.f : ewh[j];
    uint4 g0 = *(const uint4*)(h + (size_t)s0 * 256 + choff);
    dsum += w0;
    float2 p0 = up2(g0.x), p1 = up2(g0.y), p2 = up2(g0.z), p3 = up2(g0.w);
    accA.x = fmaf(w0, p0.x, accA.x); accA.y = fmaf(w0, p0.y, accA.y);
    accA.z = fmaf(w0, p1.x, accA.z); accA.w = fmaf(w0, p1.y, accA.w);
    accB.x = fmaf(w0, p2.x, accB.x); accB.y = fmaf(w0, p2.y, accB.y);
    accB.z = fmaf(w0, p3.x, accB.z); accB.w = fmaf(w0, p3.y, accB.w);
  }
  // combine the two half-waves (lane l <-> l+32, same channels/head)
  accA.x += __shfl_xor(accA.x, 32); accA.y += __shfl_xor(accA.y, 32);
  accA.z += __shfl_xor(accA.z, 32); accA.w += __shfl_xor(accA.w, 32);
  accB.x += __shfl_xor(accB.x, 32); accB.y += __shfl_xor(accB.y, 32);
  accB.z += __shfl_xor(accB.z, 32); accB.w += __shfl_xor(accB.w, 32);
  dsum += __shfl_xor(dsum, 32);
  if (half == 0) {
    const float inv = 1.f / (dsum + 1e-16f);
    const float4 bA = *(const float4*)(bias + lc * 8);
    const float4 bB = *(const float4*)(bias + lc * 8 + 4);
    float v;
    us8 o;
    v = accA.x * inv + bA.x; o[0] = f2h(v > 0.f ? v : expm1f(v));
    v = accA.y * inv + bA.y; o[1] = f2h(v > 0.f ? v : expm1f(v));
    v = accA.z * inv + bA.z; o[2] = f2h(v > 0.f ? v : expm1f(v));
    v = accA.w * inv + bA.w; o[3] = f2h(v > 0.f ? v : expm1f(v));
    v = accB.x * inv + bB.x; o[4] = f2h(v > 0.f ? v : expm1f(v));
    v = accB.y * inv + bB.y; o[5] = f2h(v > 0.f ? v : expm1f(v));
    v = accB.z * inv + bB.z; o[6] = f2h(v > 0.f ? v : expm1f(v));
    v = accB.w * inv + bB.w; o[7] = f2h(v > 0.f ? v : expm1f(v));
    *(us8*)(out + (size_t)n * 256 + choff) = o;
  }
}

// ---------------- graph max-pool from fp16 (batch is sorted) -------------------
#define PNB 32
__global__ __launch_bounds__(256) void pool_max(
    const unsigned short* __restrict__ fb, const int* __restrict__ batch,
    float* __restrict__ pooled, int N_) {
  const int c2 = threadIdx.x & 127;        // channels 2*c2, 2*c2+1
  const int slot = threadIdx.x >> 7;       // 2 slots x 16 nodes
  const int ns = blockIdx.x * PNB + slot * 16;
  const int ne = min(ns + 16, N_);
  if (ns >= N_) return;
  float r0 = NEG_INF, r1 = NEG_INF;
  int g = batch[ns];
#pragma unroll 4
  for (int n = ns; n < ne; ++n) {
    int gn = batch[n];
    unsigned int w = *(const unsigned int*)(fb + (size_t)n * 256 + c2 * 2);
    if (gn != g) {
      atomicMaxF(&pooled[(size_t)g * 256 + c2 * 2], r0);
      atomicMaxF(&pooled[(size_t)g * 256 + c2 * 2 + 1], r1);
      r0 = r1 = NEG_INF; g = gn;
    }
    float2 xv = up2(w);
    r0 = fmaxf(r0, xv.x);
    r1 = fmaxf(r1, xv.y);
  }
  atomicMaxF(&pooled[(size_t)g * 256 + c2 * 2], r0);
  atomicMaxF(&pooled[(size_t)g * 256 + c2 * 2 + 1], r1);
}

// ---------------- head: fixup -inf, lin1 (256->128), lin2 (128->2) ------------
__global__ __launch_bounds__(128) void head_k(
    const float* __restrict__ pooled, const float* __restrict__ w1,
    const float* __restrict__ b1, const float* __restrict__ w2,
    const float* __restrict__ b2, float* __restrict__ out) {
  __shared__ float ps[256];
  __shared__ float z1[128];
  int g = blockIdx.x;
  int t = threadIdx.x;
  for (int i = t; i < 256; i += 128) {
    float v = pooled[(size_t)g * 256 + i];
    if (v < -1e37f) v = 0.f;   // empty-graph guard (isneginf -> 0)
    ps[i] = v;
  }
  __syncthreads();
  float a = b1[t];
  for (int k = 0; k < 256; ++k) a = fmaf(ps[k], w1[k * 128 + t], a);
  z1[t] = a;
  __syncthreads();
  if (t < 2) {
    float a2 = b2[t];
    for (int j = 0; j < 128; ++j) a2 = fmaf(z1[j], w2[j * 2 + t], a2);
    out[g * 2 + t] = a2;
  }
}

// ---------------- driver --------------------------------------------------------
extern "C" void kernel_launch(void* const* d_in, const int* in_sizes, int n_in,
                              void* d_out, int out_size, void* d_ws, size_t ws_size,
                              hipStream_t stream) {
  const int N = in_sizes[2];         // batch array length = #nodes
  const int E = in_sizes[1] / 2;     // edge_index is [2,E]
  const int G = out_size / 2;        // output [G,2]
  const int T = E + N;               // CSR slots (incl. self loops)
  const int Tpad = ((T + 3) / 4) * 4;
  const int Npad = ((N + 127) / 128) * 128;

  const float* x     = (const float*)d_in[0];
  const int*   ei    = (const int*)d_in[1];
  const int*   src   = ei;
  const int*   dst   = ei + E;
  const int*   batch = (const int*)d_in[2];
  const float* W1    = (const float*)d_in[3];
  const float* atts1 = (const float*)d_in[4];
  const float* attd1 = (const float*)d_in[5];
  const float* b1    = (const float*)d_in[6];
  const float* W2    = (const float*)d_in[7];
  const float* atts2 = (const float*)d_in[8];
  const float* attd2 = (const float*)d_in[9];
  const float* b2    = (const float*)d_in[10];
  const float* l1w   = (const float*)d_in[11];
  const float* l1b   = (const float*)d_in[12];
  const float* l2w   = (const float*)d_in[13];
  const float* l2b   = (const float*)d_in[14];

  uintptr_t p = (uintptr_t)d_ws;
  auto alloc = [&](size_t bytes) -> void* {
    p = (p + 255) & ~(uintptr_t)255;
    void* r = (void*)p;
    p += bytes;
    return r;
  };
  const int nb = (N + SCB - 1) / SCB;
  unsigned short* hbuf = (unsigned short*)alloc((size_t)N * 256 * 2);     // fp16 h (GEMM out)
  unsigned short* xbuf = (unsigned short*)alloc((size_t)Npad * 256 * 2);  // fp16 x
  unsigned short* fbuf = (unsigned short*)alloc((size_t)Npad * 256 * 2);  // fp16 agg out
  float* a_s    = (float*)alloc((size_t)N * 4 * 4);
  float* a_d    = (float*)alloc((size_t)N * 4 * 4);
  float* pooled = (float*)alloc((size_t)G * 256 * 4);
  int*   count  = (int*)alloc((size_t)N * 4);
  int*   rowptr = (int*)alloc((size_t)(N + 1) * 4);
  int*   nxt    = (int*)alloc((size_t)N * 4);
  int*   colx   = (int*)alloc((size_t)Tpad * 4);
  int*   rowx   = (int*)alloc((size_t)Tpad * 4);
  float* ewt    = (float*)alloc((size_t)Tpad * 4 * 4);
  int*   bsum   = (int*)alloc((size_t)nb * 4);
  int*   boff   = (int*)alloc((size_t)(nb + 1) * 4);
  unsigned short* wt1 = (unsigned short*)alloc(256 * 256 * 2);
  unsigned short* wt2 = (unsigned short*)alloc(256 * 256 * 2);

  dim3 blk(256);
  dim3 gemmGrid(Npad / 128, 2);
  int initRange = max(N, G * 256);
  int xtot = N * 256;

  // pre-passes + CSR build (shared by both layers) + init
  conv_wx<<<512 + (xtot / 4 + 255) / 256, blk, 0, stream>>>(W1, W2, wt1, wt2, x, xbuf, xtot);
  init_misc<<<(initRange + 255) / 256, blk, 0, stream>>>(count, pooled, N, G);
  hist_k<<<(E + 255) / 256, blk, 0, stream>>>(dst, count, E);
  scan_phaseA<<<nb, blk, 0, stream>>>(count, bsum, N);
  scan_phaseB<<<1, blk, 0, stream>>>(bsum, boff, nb);
  scan_phaseC<<<nb, blk, 0, stream>>>(count, boff, rowptr, nxt, N, nb);
  scatter_k<<<(T + 255) / 256, blk, 0, stream>>>(src, dst, nxt, colx, rowx, E, N);

  // ---- layer 1
  gemm_mfma<<<gemmGrid, blk, 0, stream>>>(xbuf, wt1, atts1, attd1, hbuf, a_s, a_d, N);
  edge_w<<<(T + 255) / 256, blk, 0, stream>>>(colx, rowx, a_s, a_d, ewt, Tpad);
  agg<<<(N + 3) / 4, blk, 0, stream>>>(hbuf, rowptr, colx, ewt, Tpad, b1, fbuf, N);

  // ---- layer 2
  gemm_mfma<<<gemmGrid, blk, 0, stream>>>(fbuf, wt2, atts2, attd2, hbuf, a_s, a_d, N);
  edge_w<<<(T + 255) / 256, blk, 0, stream>>>(colx, rowx, a_s, a_d, ewt, Tpad);
  agg<<<(N + 3) / 4, blk, 0, stream>>>(hbuf, rowptr, colx, ewt, Tpad, b2, fbuf, N);

  // ---- pool + head
  pool_max<<<(N + PNB - 1) / PNB, blk, 0, stream>>>(fbuf, batch, pooled, N);
  head_k<<<G, 128, 0, stream>>>(pooled, l1w, l1b, l2w, l2b, (float*)d_out);
}